// Round 9
// baseline (724.837 us; speedup 1.0000x reference)
//
#include <hip/hip_runtime.h>
#include <stdint.h>

#define B_   256
#define NPG  512
#define NG   131072
#define EPG  4096
#define NQPG 16
#define NQ   4096
#define EQPG 128
#define L_   2

typedef __attribute__((ext_vector_type(8))) short short8;
typedef __attribute__((ext_vector_type(4))) float floatx4;

__device__ inline float bf2f(unsigned short u){
    union { unsigned int i; float f; } x; x.i = ((unsigned int)u) << 16; return x.f;
}
__device__ inline unsigned short f2bf(float f){
    union { float f; unsigned int i; } x; x.f = f;
    unsigned int r = x.i + 0x7fff + ((x.i >> 16) & 1);  // RNE
    return (unsigned short)(r >> 16);
}
__device__ inline float d2(unsigned int a, unsigned int b, float c){
#if __has_builtin(__builtin_amdgcn_fdot2_f32_bf16)
    typedef __attribute__((ext_vector_type(2))) __bf16 bf16x2;
    union { unsigned int u; bf16x2 v; } xa, xb;
    xa.u = a; xb.u = b;
    return __builtin_amdgcn_fdot2_f32_bf16(xa.v, xb.v, c, false);
#else
    union { unsigned int u; float f; } la, ha, lb, hb;
    la.u = a << 16; ha.u = a & 0xffff0000u;
    lb.u = b << 16; hb.u = b & 0xffff0000u;
    return fmaf(la.f, lb.f, fmaf(ha.f, hb.f, c));
#endif
}
__device__ inline float dot8(uint4 a, uint4 b){
    return d2(a.x,b.x, d2(a.y,b.y, d2(a.z,b.z, d2(a.w,b.w, 0.f))));
}

// ---- transpose weights (fp32 in) to [N][K] bf16 ----
__global__ void k_transpose(const float* Wg, const float* Wq,
                            const float* W1r, const float* W2r,
                            unsigned short* WgT, unsigned short* WqT,
                            unsigned short* W1aT, unsigned short* W2rT){
    int idx = blockIdx.x*256 + threadIdx.x;
    if (idx < 8192){
        int k = idx >> 7, n = idx & 127; WgT[n*64 + k] = f2bf(Wg[idx]);
    } else if (idx < 16384){
        int i = idx - 8192; int k = i>>7, n = i&127; WqT[n*64+k] = f2bf(Wq[i]);
    } else if (idx < 49152){
        int i = idx - 16384; int l = i >> 14; int j = i & 16383; int k = j>>7, n = j&127;
        W1aT[l*16384 + n*128 + k] = f2bf(W1r[l*32768 + j]);
    } else {
        int i = idx - 49152; int l = i >> 14; int j = i & 16383; int k = j>>7, n = j&127;
        W2rT[l*16384 + n*128 + k] = f2bf(W2r[i]);
    }
}

// ---- one-shot CSR build per data graph ----
__global__ __launch_bounds__(256) void k_csr(const int* __restrict__ g_src,
        const int* __restrict__ g_dst,
        unsigned short* __restrict__ srcl_g, unsigned short* __restrict__ dstl_g,
        unsigned short* __restrict__ csr_g, int* __restrict__ off_g,
        int* __restrict__ cnt_g){
    int g = blockIdx.x, t = threadIdx.x, lane = t & 63;
    __shared__ int cnt[NPG], off[NPG], woff[NPG];
    __shared__ int gscan[64];
    int gbase = g*NPG; size_t ebase = (size_t)g*EPG;
    for (int n=t;n<NPG;n+=256) cnt[n]=0;
    __syncthreads();
    for (int i=t;i<EPG;i+=256){
        int s = g_src[ebase+i]-gbase, d = g_dst[ebase+i]-gbase;
        srcl_g[ebase+i]=(unsigned short)s; dstl_g[ebase+i]=(unsigned short)d;
        atomicAdd(&cnt[d],1);
    }
    __syncthreads();
    if (t < 64){
        int s=0;
        #pragma unroll
        for (int j=0;j<8;j++) s += cnt[t*8+j];
        int v=s;
        #pragma unroll
        for (int o=1;o<64;o<<=1){ int u=__shfl_up(v,o); if (lane>=o) v+=u; }
        gscan[t]=v;
    }
    __syncthreads();
    for (int n=t;n<NPG;n+=256){
        int grp=n>>3; int base = grp?gscan[grp-1]:0;
        for (int j=grp*8;j<n;j++) base+=cnt[j];
        off[n]=base; woff[n]=base;
    }
    __syncthreads();
    for (int i=t;i<EPG;i+=256){
        int d = g_dst[ebase+i]-gbase;
        int pos = atomicAdd(&woff[d],1);
        csr_g[ebase+pos]=(unsigned short)i;
    }
    __syncthreads();
    for (int n=t;n<NPG;n+=256){
        off_g[g*NPG+n]=off[n]; cnt_g[g*NPG+n]=cnt[n];
    }
}

// ---- proj (swapped MFMA): each lane owns one row, 4 consecutive cols/tile ----
__global__ __launch_bounds__(256) void k_proj(const float* __restrict__ A,
        const unsigned short* __restrict__ Wt, const float* __restrict__ bias,
        unsigned short* __restrict__ out, float* __restrict__ nrm2){
    const int K = 64;
    int wave = threadIdx.x >> 6, lane = threadIdx.x & 63;
    int quad = lane >> 4, l16 = lane & 15;
    int wrow = blockIdx.x*64 + wave*16;
    floatx4 acc[8];
    #pragma unroll
    for (int t=0;t<8;t++){
        #pragma unroll
        for (int r=0;r<4;r++) acc[t][r]=0.f;
    }
    #pragma unroll
    for (int ks = 0; ks < 2; ks++){
        int koff = ks*32 + quad*8;
        const float* ap = A + (size_t)(wrow+l16)*K + koff;
        short8 a;
        #pragma unroll
        for (int j=0;j<8;j++) a[j] = (short)f2bf(ap[j]);
        #pragma unroll
        for (int t=0;t<8;t++){
            short8 b = *(const short8*)(Wt + (size_t)(t*16+l16)*K + koff);
            acc[t] = __builtin_amdgcn_mfma_f32_16x16x32_bf16(b, a, acc[t], 0,0,0);
        }
    }
    int row = wrow + l16;
    float ss = 0.f;
    #pragma unroll
    for (int t=0;t<8;t++){
        int col0 = t*16 + quad*4;
        float v0 = acc[t][0] + bias[col0+0];
        float v1 = acc[t][1] + bias[col0+1];
        float v2 = acc[t][2] + bias[col0+2];
        float v3 = acc[t][3] + bias[col0+3];
        ss += v0*v0 + v1*v1 + v2*v2 + v3*v3;
        uint2 ov;
        ov.x = (unsigned int)f2bf(v0) | ((unsigned int)f2bf(v1)<<16);
        ov.y = (unsigned int)f2bf(v2) | ((unsigned int)f2bf(v3)<<16);
        *(uint2*)(out + (size_t)row*128 + col0) = ov;
    }
    if (nrm2){
        ss += __shfl_xor(ss, 16);
        ss += __shfl_xor(ss, 32);
        if (lane < 16) nrm2[wrow + lane] = ss;
    }
}

// ---- query AGNN + per-graph sum + Qg + fused cg2 = hqa @ W1r[l][128:256,:] ----
__global__ __launch_bounds__(128) void k_qagnn(unsigned short* __restrict__ h_q,
        const int* __restrict__ q_src, const int* __restrict__ q_dst,
        const float* __restrict__ beta_p, float* __restrict__ hqa,
        float* __restrict__ Qg, const float* __restrict__ W1r_l,
        float* __restrict__ cg2){
    int g = blockIdx.x, t = threadIdx.x;
    __shared__ float h[NQPG][132];
    __shared__ float e[EQPG], w[EQPG];
    __shared__ float inv[NQPG], mx[NQPG], den[NQPG];
    __shared__ int srcl[EQPG], dstl[EQPG], csr[EQPG];
    __shared__ int cnt[NQPG], off[NQPG], woff[NQPG];
    __shared__ float part[128];
    float beta = beta_p[0];
    for (int idx=t; idx<NQPG*128; idx+=128){
        int n = idx>>7, d = idx&127;
        h[n][d] = bf2f(h_q[(size_t)(g*NQPG+n)*128 + d]);
    }
    if (t<NQPG){ cnt[t]=0; mx[t]=0.f; den[t]=0.f; }
    __syncthreads();
    { int n=t>>3, c=t&7; float s=0;
      for (int d=c*16; d<c*16+16; d++){ float v=h[n][d]; s+=v*v; }
      part[t]=s; }
    __syncthreads();
    if (t<NQPG){ float s=0; for(int c=0;c<8;c++) s+=part[t*8+c]; inv[t]=rsqrtf(s+1e-24f); }
    __syncthreads();
    { int eidx = g*EQPG + t;
      int s = q_src[eidx] - g*NQPG, d = q_dst[eidx] - g*NQPG;
      srcl[t]=s; dstl[t]=d;
      float dot=0;
      for (int k=0;k<128;k++) dot += h[s][k]*h[d][k];
      e[t] = beta*dot*inv[s]*inv[d];
      atomicAdd(&cnt[d],1); }
    __syncthreads();
    if (t==0){ int o=0; for(int i=0;i<NQPG;i++){ off[i]=o; o+=cnt[i]; } }
    __syncthreads();
    if (t<NQPG){ woff[t]=off[t];
        if (cnt[t] > 0){
            float mm=-1e30f, dd=0.f;
            for (int j=0;j<EQPG;j++) if (dstl[j]==t) mm = fmaxf(mm, e[j]);
            for (int j=0;j<EQPG;j++) if (dstl[j]==t) dd += __expf(e[j]-mm);
            mx[t]=mm; den[t]=dd;
        } }
    __syncthreads();
    { int d = dstl[t];
      float dd = den[d];
      w[t] = dd > 0.f ? __expf(e[t]-mx[d]) / dd : 0.f;
      int pos = atomicAdd(&woff[d],1);
      csr[pos]=t; }
    __syncthreads();
    float aggr=0.f;
    { int d = t;
      for (int n=0;n<NQPG;n++){
          float acc=0.f;
          int o=off[n], c=cnt[n];
          for (int j=o;j<o+c;j++){ int ei=csr[j]; acc += w[ei]*h[srcl[ei]][d]; }
          h_q[(size_t)(g*NQPG+n)*128 + d] = f2bf(acc);
          aggr += acc;
      }
      hqa[g*128+d]=aggr; }
    __syncthreads();
    part[t] = aggr*aggr;
    h[0][t] = aggr;          // stash hqa row for cvec (h no longer needed)
    __syncthreads();
    for (int s2=64; s2>0; s2>>=1){
        if (t<s2) part[t]+=part[t+s2];
        __syncthreads();
    }
    if (t==0) Qg[g]=part[0];
    // fused cvec: cg2[j] = sum_k hqa[k] * W1r_l[(128+k)*128 + j]
    float accc = 0.f;
    for (int k=0;k<128;k++) accc += h[0][k] * W1r_l[(128+k)*128 + t];
    cg2[g*128+t] = accc;
}

// ---- fused data-graph layer: AGNN (edge softmax + gather) + MLP, all per graph ----
// 119 KB dynamic LDS => 1 block/CU (16 waves = 4 waves/EU). Declare exactly that
// occupancy so the allocator gets the full 128-VGPR budget (R8: default cap of 64
// VGPRs caused ~430 MB/dispatch of scratch spill traffic).
#define SMEM_GL 119296
__global__ __launch_bounds__(1024, 4) void k_glayer(
        const unsigned short* __restrict__ h_in, const float* __restrict__ nrm2_in,
        const float* __restrict__ Qg,
        const unsigned short* __restrict__ srcl_g, const unsigned short* __restrict__ dstl_g,
        const unsigned short* __restrict__ csr_g, const int* __restrict__ off_g,
        const int* __restrict__ cnt_g, const float* __restrict__ beta_p,
        const unsigned short* __restrict__ W1t, const float* __restrict__ b1,
        const float* __restrict__ cg2, const unsigned short* __restrict__ W2t,
        const float* __restrict__ b2,
        unsigned short* __restrict__ h_out, float* __restrict__ nrm2_out){
    extern __shared__ __align__(16) char smem[];
    float* e             = (float*)(smem);                     // 16384
    unsigned short* srcl = (unsigned short*)(smem + 16384);    // 8192
    unsigned short* dstl = (unsigned short*)(smem + 24576);    // 8192
    unsigned short* csr  = (unsigned short*)(smem + 32768);    // 8192
    float* den           = (float*)(smem + 40960);             // 2048
    float* inv           = (float*)(smem + 43008);             // 2048
    int*   off           = (int*)(smem + 45056);               // 2048
    unsigned short* cnts = (unsigned short*)(smem + 47104);    // 1024
    float* b1s           = (float*)(smem + 48128);             // 512
    float* b2s           = (float*)(smem + 48640);             // 512
    float* cgs           = (float*)(smem + 49152);             // 512
    unsigned short* wbufA= (unsigned short*)(smem + 49664);    // 16*2176*2 = 69632

    int g = blockIdx.x, t = threadIdx.x;
    int wave = t>>6, lane = t&63, sub = lane>>4, sl = lane&15;
    int quad = sub, l16 = sl;
    float beta = beta_p[0];
    float Q = Qg[g];
    int gbase = g*NPG;
    size_t ebase = (size_t)g*EPG;
    for (int i=t;i<EPG;i+=1024){
        srcl[i]=srcl_g[ebase+i]; dstl[i]=dstl_g[ebase+i]; csr[i]=csr_g[ebase+i];
    }
    for (int n=t;n<NPG;n+=1024){
        inv[n]=rsqrtf(nrm2_in[gbase+n]+Q+1e-24f);
        off[n]=off_g[g*NPG+n];
        cnts[n]=(unsigned short)cnt_g[g*NPG+n];
        den[n]=0.f;
    }
    if (t<128) b1s[t]=b1[t];
    else if (t<256) b2s[t-128]=b2[t-128];
    else if (t<384) cgs[t-256]=cg2[g*128 + (t-256)];
    __syncthreads();
    // phase A: edge logits, 16 lanes per edge; denominators via LDS atomic
    for (int ei = wave*4 + sub; ei < EPG; ei += 64){
        int s = srcl[ei], d = dstl[ei];
        uint4 us = *(const uint4*)(h_in + (size_t)(gbase+s)*128 + sl*8);
        uint4 ud = *(const uint4*)(h_in + (size_t)(gbase+d)*128 + sl*8);
        float v = dot8(us, ud);
        v += __shfl_xor(v,1); v += __shfl_xor(v,2);
        v += __shfl_xor(v,4); v += __shfl_xor(v,8);
        if (sl==0){
            float ex = __expf(beta * (v + Q) * inv[s]*inv[d]);
            e[ei] = ex;
            atomicAdd(&den[d], ex);
        }
    }
    __syncthreads();
    // phase B: wave handles nodes [wave*32, wave*32+32) in 2 chunks of 16
    unsigned short* wb = wbufA + wave*2176;  // 16 rows x 136
    for (int c=0;c<2;c++){
        int nb = wave*32 + c*16;
        // gather 16 nodes into wave-private LDS (4 sub-groups x 4 rows)
        for (int r4=0;r4<4;r4++){
            int rl = sub + r4*4;
            int n = nb + rl;
            int cN = cnts[n];
            uint4 ov;
            if (cN > 0){
                int o = off[n];
                float invd = __frcp_rn(den[n]);
                float a0=0,a1=0,a2=0,a3=0,a4=0,a5=0,a6=0,a7=0;
                for (int j=0;j<cN;j++){
                    int ei = csr[o+j];
                    float wg = e[ei] * invd;
                    int s = srcl[ei];
                    uint4 us = *(const uint4*)(h_in + (size_t)(gbase+s)*128 + sl*8);
                    a0 = fmaf(wg, bf2f((unsigned short)(us.x&0xffff)), a0);
                    a1 = fmaf(wg, bf2f((unsigned short)(us.x>>16)),   a1);
                    a2 = fmaf(wg, bf2f((unsigned short)(us.y&0xffff)), a2);
                    a3 = fmaf(wg, bf2f((unsigned short)(us.y>>16)),   a3);
                    a4 = fmaf(wg, bf2f((unsigned short)(us.z&0xffff)), a4);
                    a5 = fmaf(wg, bf2f((unsigned short)(us.z>>16)),   a5);
                    a6 = fmaf(wg, bf2f((unsigned short)(us.w&0xffff)), a6);
                    a7 = fmaf(wg, bf2f((unsigned short)(us.w>>16)),   a7);
                }
                ov.x = (unsigned int)f2bf(a0) | ((unsigned int)f2bf(a1)<<16);
                ov.y = (unsigned int)f2bf(a2) | ((unsigned int)f2bf(a3)<<16);
                ov.z = (unsigned int)f2bf(a4) | ((unsigned int)f2bf(a5)<<16);
                ov.w = (unsigned int)f2bf(a6) | ((unsigned int)f2bf(a7)<<16);
            } else {
                ov.x=0; ov.y=0; ov.z=0; ov.w=0;
            }
            *(uint4*)(wb + rl*136 + sl*8) = ov;
        }
        __syncthreads();
        // GEMM1: read all A-frags to regs first (so wb can be overwritten)
        short8 af[4];
        #pragma unroll
        for (int ks=0;ks<4;ks++) af[ks] = *(const short8*)(wb + l16*136 + ks*32 + quad*8);
        floatx4 acc[8];
        #pragma unroll
        for (int t8=0;t8<8;t8++){
            #pragma unroll
            for (int r=0;r<4;r++) acc[t8][r]=0.f;
        }
        #pragma unroll
        for (int ks=0;ks<4;ks++){
            int koff = ks*32 + quad*8;
            #pragma unroll
            for (int t8=0;t8<8;t8++){
                short8 b = *(const short8*)(W1t + (size_t)(t8*16+l16)*128 + koff);
                acc[t8] = __builtin_amdgcn_mfma_f32_16x16x32_bf16(b, af[ks], acc[t8], 0,0,0);
            }
        }
        float dg = (cnts[nb + l16] > 0) ? 1.f : 0.f;
        #pragma unroll
        for (int t8=0;t8<8;t8++){
            int col0 = t8*16 + quad*4;
            float4 bv = *(const float4*)(b1s + col0);
            float4 cv = *(const float4*)(cgs + col0);
            float v0 = acc[t8][0] + bv.x + dg*cv.x; v0 = v0>0.f?v0:0.f;
            float v1 = acc[t8][1] + bv.y + dg*cv.y; v1 = v1>0.f?v1:0.f;
            float v2 = acc[t8][2] + bv.z + dg*cv.z; v2 = v2>0.f?v2:0.f;
            float v3 = acc[t8][3] + bv.w + dg*cv.w; v3 = v3>0.f?v3:0.f;
            uint2 ov;
            ov.x = (unsigned int)f2bf(v0) | ((unsigned int)f2bf(v1)<<16);
            ov.y = (unsigned int)f2bf(v2) | ((unsigned int)f2bf(v3)<<16);
            *(uint2*)(wb + l16*136 + col0) = ov;
        }
        __syncthreads();
        // GEMM2
        #pragma unroll
        for (int ks=0;ks<4;ks++) af[ks] = *(const short8*)(wb + l16*136 + ks*32 + quad*8);
        floatx4 acc2[8];
        #pragma unroll
        for (int t8=0;t8<8;t8++){
            #pragma unroll
            for (int r=0;r<4;r++) acc2[t8][r]=0.f;
        }
        #pragma unroll
        for (int ks=0;ks<4;ks++){
            int koff = ks*32 + quad*8;
            #pragma unroll
            for (int t8=0;t8<8;t8++){
                short8 b = *(const short8*)(W2t + (size_t)(t8*16+l16)*128 + koff);
                acc2[t8] = __builtin_amdgcn_mfma_f32_16x16x32_bf16(b, af[ks], acc2[t8], 0,0,0);
            }
        }
        int row = gbase + nb + l16;
        float ss = 0.f;
        #pragma unroll
        for (int t8=0;t8<8;t8++){
            int col0 = t8*16 + quad*4;
            float4 bv = *(const float4*)(b2s + col0);
            float v0 = acc2[t8][0] + bv.x;
            float v1 = acc2[t8][1] + bv.y;
            float v2 = acc2[t8][2] + bv.z;
            float v3 = acc2[t8][3] + bv.w;
            ss += v0*v0 + v1*v1 + v2*v2 + v3*v3;
            uint2 ov;
            ov.x = (unsigned int)f2bf(v0) | ((unsigned int)f2bf(v1)<<16);
            ov.y = (unsigned int)f2bf(v2) | ((unsigned int)f2bf(v3)<<16);
            *(uint2*)(h_out + (size_t)row*128 + col0) = ov;
        }
        ss += __shfl_xor(ss, 16);
        ss += __shfl_xor(ss, 32);
        if (lane < 16) nrm2_out[gbase + nb + lane] = ss;
        __syncthreads();
    }
}

// ---- fused per-graph sum + predictor ----
__global__ __launch_bounds__(512) void k_hgpred(const unsigned short* __restrict__ h_g,
        const float* __restrict__ Wp1, const float* __restrict__ bp1,
        const float* __restrict__ Wp2, const float* __restrict__ bp2,
        float* __restrict__ y){
    __shared__ float red[32][128];
    __shared__ float hsum[128];
    __shared__ float red2[128];
    int g = blockIdx.x, t = threadIdx.x;
    int c = t & 15, r0 = t >> 4;
    float s[8];
    #pragma unroll
    for (int k=0;k<8;k++) s[k]=0.f;
    for (int i=0;i<16;i++){
        int row = r0 + i*32;
        uint4 u = *(const uint4*)(h_g + (size_t)(g*NPG + row)*128 + c*8);
        s[0] += bf2f((unsigned short)(u.x&0xffff)); s[1] += bf2f((unsigned short)(u.x>>16));
        s[2] += bf2f((unsigned short)(u.y&0xffff)); s[3] += bf2f((unsigned short)(u.y>>16));
        s[4] += bf2f((unsigned short)(u.z&0xffff)); s[5] += bf2f((unsigned short)(u.z>>16));
        s[6] += bf2f((unsigned short)(u.w&0xffff)); s[7] += bf2f((unsigned short)(u.w>>16));
    }
    #pragma unroll
    for (int k=0;k<8;k++) red[r0][c*8+k] = s[k];
    __syncthreads();
    if (t < 128){
        float a = 0.f;
        #pragma unroll
        for (int r=0;r<32;r++) a += red[r][t];
        hsum[t] = a;
    }
    __syncthreads();
    if (t < 128){
        float acc = bp1[t];
        for (int k=0;k<128;k++) acc += hsum[k]*Wp1[k*128+t];
        acc = fmaxf(acc, 0.f);
        red2[t] = acc * Wp2[t];
    }
    __syncthreads();
    for (int s2=64; s2>0; s2>>=1){
        if (t<s2) red2[t]+=red2[t+s2];
        __syncthreads();
    }
    if (t==0) y[g] = red2[0] + bp2[0];
}

extern "C" void kernel_launch(void* const* d_in, const int* in_sizes, int n_in,
                              void* d_out, int out_size, void* d_ws, size_t ws_size,
                              hipStream_t stream) {
    const float* X    = (const float*)d_in[0];
    const float* X_q  = (const float*)d_in[1];
    const int* g_src = (const int*)d_in[2];
    const int* g_dst = (const int*)d_in[3];
    const int* q_src = (const int*)d_in[5];
    const int* q_dst = (const int*)d_in[6];
    const float* Wg   = (const float*)d_in[8];
    const float* bg   = (const float*)d_in[9];
    const float* Wq   = (const float*)d_in[10];
    const float* bq   = (const float*)d_in[11];
    const float* betas_g = (const float*)d_in[12];
    const float* betas_q = (const float*)d_in[13];
    const float* W1r  = (const float*)d_in[14];
    const float* b1r  = (const float*)d_in[15];
    const float* W2r  = (const float*)d_in[16];
    const float* b2r  = (const float*)d_in[17];
    const float* Wp1  = (const float*)d_in[18];
    const float* bp1  = (const float*)d_in[19];
    const float* Wp2  = (const float*)d_in[20];
    const float* bp2  = (const float*)d_in[21];

    uint8_t* w = (uint8_t*)d_ws;
    unsigned short* h_ping = (unsigned short*)w;  w += (size_t)NG*128*2;
    unsigned short* h_pong = (unsigned short*)w;  w += (size_t)NG*128*2;
    unsigned short* h_q  = (unsigned short*)w;    w += (size_t)NQ*128*2;
    float* nrm2_ping = (float*)w;                 w += (size_t)NG*4;
    float* nrm2_pong = (float*)w;                 w += (size_t)NG*4;
    float* hqa   = (float*)w;                     w += (size_t)B_*128*4;
    float* Qg    = (float*)w;                     w += (size_t)B_*4*4;
    float* cg2   = (float*)w;                     w += (size_t)B_*128*4;
    unsigned short* WgT   = (unsigned short*)w;   w += 8192*2;
    unsigned short* WqT   = (unsigned short*)w;   w += 8192*2;
    unsigned short* W1aT  = (unsigned short*)w;   w += 2*16384*2;
    unsigned short* W2rT  = (unsigned short*)w;   w += 2*16384*2;
    unsigned short* srcl_g = (unsigned short*)w;  w += (size_t)B_*EPG*2;
    unsigned short* dstl_g = (unsigned short*)w;  w += (size_t)B_*EPG*2;
    unsigned short* csr_g  = (unsigned short*)w;  w += (size_t)B_*EPG*2;
    int* off_g = (int*)w;                         w += (size_t)B_*NPG*4;
    int* cnt_g = (int*)w;                         w += (size_t)B_*NPG*4;

    static bool attr_done = false;
    if (!attr_done){
        hipFuncSetAttribute((const void*)k_glayer,
                            hipFuncAttributeMaxDynamicSharedMemorySize, SMEM_GL);
        attr_done = true;
    }

    k_transpose<<<320,256,0,stream>>>(Wg,Wq,W1r,W2r,WgT,WqT,W1aT,W2rT);
    k_csr<<<B_,256,0,stream>>>(g_src,g_dst,srcl_g,dstl_g,csr_g,off_g,cnt_g);
    k_proj<<<NG/64,256,0,stream>>>(X,   WgT, bg, h_ping, nrm2_ping);
    k_proj<<<NQ/64,256,0,stream>>>(X_q, WqT, bq, h_q, nullptr);
    unsigned short* hin = h_ping;  float* nin = nrm2_ping;
    unsigned short* hot = h_pong;  float* not_ = nrm2_pong;
    for (int l=0;l<L_;l++){
        k_qagnn<<<B_,128,0,stream>>>(h_q, q_src, q_dst, betas_q + l, hqa, Qg,
                                     W1r + l*32768, cg2);
        k_glayer<<<B_,1024,SMEM_GL,stream>>>(hin, nin, Qg, srcl_g, dstl_g, csr_g,
                                             off_g, cnt_g, betas_g + l,
                                             W1aT + l*16384, b1r + l*128, cg2,
                                             W2rT + l*16384, b2r + l*128, hot, not_);
        unsigned short* th = hin; hin = hot; hot = th;
        float* tn = nin; nin = not_; not_ = tn;
    }
    k_hgpred<<<B_,512,0,stream>>>(hin, Wp1, bp1, Wp2, bp2, (float*)d_out);
}

// Round 10
// 413.024 us; speedup vs baseline: 1.7550x; 1.7550x over previous
//
#include <hip/hip_runtime.h>
#include <stdint.h>

#define B_   256
#define NPG  512
#define NG   131072
#define EPG  4096
#define NQPG 16
#define NQ   4096
#define EQPG 128
#define L_   2

typedef __attribute__((ext_vector_type(8))) short short8;
typedef __attribute__((ext_vector_type(4))) float floatx4;

__device__ inline float bf2f(unsigned short u){
    union { unsigned int i; float f; } x; x.i = ((unsigned int)u) << 16; return x.f;
}
__device__ inline unsigned short f2bf(float f){
    union { float f; unsigned int i; } x; x.f = f;
    unsigned int r = x.i + 0x7fff + ((x.i >> 16) & 1);  // RNE
    return (unsigned short)(r >> 16);
}
__device__ inline float d2(unsigned int a, unsigned int b, float c){
#if __has_builtin(__builtin_amdgcn_fdot2_f32_bf16)
    typedef __attribute__((ext_vector_type(2))) __bf16 bf16x2;
    union { unsigned int u; bf16x2 v; } xa, xb;
    xa.u = a; xb.u = b;
    return __builtin_amdgcn_fdot2_f32_bf16(xa.v, xb.v, c, false);
#else
    union { unsigned int u; float f; } la, ha, lb, hb;
    la.u = a << 16; ha.u = a & 0xffff0000u;
    lb.u = b << 16; hb.u = b & 0xffff0000u;
    return fmaf(la.f, lb.f, fmaf(ha.f, hb.f, c));
#endif
}
__device__ inline float dot8(uint4 a, uint4 b){
    return d2(a.x,b.x, d2(a.y,b.y, d2(a.z,b.z, d2(a.w,b.w, 0.f))));
}

// ---- transpose weights (fp32 in) to [N][K] bf16 ----
__global__ void k_transpose(const float* Wg, const float* Wq,
                            const float* W1r, const float* W2r,
                            unsigned short* WgT, unsigned short* WqT,
                            unsigned short* W1aT, unsigned short* W2rT){
    int idx = blockIdx.x*256 + threadIdx.x;
    if (idx < 8192){
        int k = idx >> 7, n = idx & 127; WgT[n*64 + k] = f2bf(Wg[idx]);
    } else if (idx < 16384){
        int i = idx - 8192; int k = i>>7, n = i&127; WqT[n*64+k] = f2bf(Wq[i]);
    } else if (idx < 49152){
        int i = idx - 16384; int l = i >> 14; int j = i & 16383; int k = j>>7, n = j&127;
        W1aT[l*16384 + n*128 + k] = f2bf(W1r[l*32768 + j]);
    } else {
        int i = idx - 49152; int l = i >> 14; int j = i & 16383; int k = j>>7, n = j&127;
        W2rT[l*16384 + n*128 + k] = f2bf(W2r[i]);
    }
}

// ---- one-shot CSR build per data graph ----
__global__ __launch_bounds__(256) void k_csr(const int* __restrict__ g_src,
        const int* __restrict__ g_dst,
        unsigned short* __restrict__ srcl_g, unsigned short* __restrict__ dstl_g,
        unsigned short* __restrict__ csr_g, int* __restrict__ off_g,
        int* __restrict__ cnt_g, float* __restrict__ degf){
    int g = blockIdx.x, t = threadIdx.x, lane = t & 63;
    __shared__ int cnt[NPG], off[NPG], woff[NPG];
    __shared__ int gscan[64];
    int gbase = g*NPG; size_t ebase = (size_t)g*EPG;
    for (int n=t;n<NPG;n+=256) cnt[n]=0;
    __syncthreads();
    for (int i=t;i<EPG;i+=256){
        int s = g_src[ebase+i]-gbase, d = g_dst[ebase+i]-gbase;
        srcl_g[ebase+i]=(unsigned short)s; dstl_g[ebase+i]=(unsigned short)d;
        atomicAdd(&cnt[d],1);
    }
    __syncthreads();
    if (t < 64){
        int s=0;
        #pragma unroll
        for (int j=0;j<8;j++) s += cnt[t*8+j];
        int v=s;
        #pragma unroll
        for (int o=1;o<64;o<<=1){ int u=__shfl_up(v,o); if (lane>=o) v+=u; }
        gscan[t]=v;
    }
    __syncthreads();
    for (int n=t;n<NPG;n+=256){
        int grp=n>>3; int base = grp?gscan[grp-1]:0;
        for (int j=grp*8;j<n;j++) base+=cnt[j];
        off[n]=base; woff[n]=base;
    }
    __syncthreads();
    for (int i=t;i<EPG;i+=256){
        int d = g_dst[ebase+i]-gbase;
        int pos = atomicAdd(&woff[d],1);
        csr_g[ebase+pos]=(unsigned short)i;
    }
    __syncthreads();
    for (int n=t;n<NPG;n+=256){
        off_g[g*NPG+n]=off[n]; cnt_g[g*NPG+n]=cnt[n];
        degf[gbase+n] = cnt[n]>0 ? 1.f : 0.f;
    }
}

// ---- proj: out_bf16[M,128] = A_f32[M,64] @ WtT + bias ; optional row sumsq ----
__global__ __launch_bounds__(256) void k_proj(const float* __restrict__ A,
        const unsigned short* __restrict__ Wt, const float* __restrict__ bias,
        unsigned short* __restrict__ out, float* __restrict__ nrm2){
    const int K = 64;
    int wave = threadIdx.x >> 6, lane = threadIdx.x & 63;
    int quad = lane >> 4, l16 = lane & 15;
    int wrow = blockIdx.x*64 + wave*16;
    floatx4 acc[8];
    #pragma unroll
    for (int t=0;t<8;t++){
        #pragma unroll
        for (int r=0;r<4;r++) acc[t][r]=0.f;
    }
    #pragma unroll
    for (int ks = 0; ks < 2; ks++){
        int koff = ks*32 + quad*8;
        const float* ap = A + (size_t)(wrow+l16)*K + koff;
        short8 a;
        #pragma unroll
        for (int j=0;j<8;j++) a[j] = (short)f2bf(ap[j]);
        #pragma unroll
        for (int t=0;t<8;t++){
            short8 b = *(const short8*)(Wt + (size_t)(t*16+l16)*K + koff);
            acc[t] = __builtin_amdgcn_mfma_f32_16x16x32_bf16(a, b, acc[t], 0,0,0);
        }
    }
    float ss[4] = {0.f,0.f,0.f,0.f};
    #pragma unroll
    for (int t=0;t<8;t++){
        int col = t*16 + l16;
        float bv = bias[col];
        #pragma unroll
        for (int r=0;r<4;r++){
            float v = acc[t][r] + bv;
            out[(size_t)(wrow + quad*4 + r)*128 + col] = f2bf(v);
            ss[r] += v*v;
        }
    }
    if (nrm2){
        #pragma unroll
        for (int r=0;r<4;r++){
            #pragma unroll
            for (int o=1;o<16;o<<=1) ss[r] += __shfl_xor(ss[r], o);
        }
        if (l16==0){
            #pragma unroll
            for (int r=0;r<4;r++) nrm2[wrow + quad*4 + r] = ss[r];
        }
    }
}

// ---- query AGNN + Qg + fused cg2 = hqa @ W1r[l][128:256,:] ----
__global__ __launch_bounds__(128) void k_qagnn(unsigned short* __restrict__ h_q,
        const int* __restrict__ q_src, const int* __restrict__ q_dst,
        const float* __restrict__ beta_p, float* __restrict__ Qg,
        const float* __restrict__ W1r_l, float* __restrict__ cg2){
    int g = blockIdx.x, t = threadIdx.x;
    __shared__ float h[NQPG][132];
    __shared__ float e[EQPG], w[EQPG];
    __shared__ float inv[NQPG], mx[NQPG], den[NQPG];
    __shared__ int srcl[EQPG], dstl[EQPG], csr[EQPG];
    __shared__ int cnt[NQPG], off[NQPG], woff[NQPG];
    __shared__ float part[128];
    float beta = beta_p[0];
    for (int idx=t; idx<NQPG*128; idx+=128){
        int n = idx>>7, d = idx&127;
        h[n][d] = bf2f(h_q[(size_t)(g*NQPG+n)*128 + d]);
    }
    if (t<NQPG){ cnt[t]=0; mx[t]=0.f; den[t]=0.f; }
    __syncthreads();
    { int n=t>>3, c=t&7; float s=0;
      for (int d=c*16; d<c*16+16; d++){ float v=h[n][d]; s+=v*v; }
      part[t]=s; }
    __syncthreads();
    if (t<NQPG){ float s=0; for(int c=0;c<8;c++) s+=part[t*8+c]; inv[t]=rsqrtf(s+1e-24f); }
    __syncthreads();
    { int eidx = g*EQPG + t;
      int s = q_src[eidx] - g*NQPG, d = q_dst[eidx] - g*NQPG;
      srcl[t]=s; dstl[t]=d;
      float dot=0;
      for (int k=0;k<128;k++) dot += h[s][k]*h[d][k];
      e[t] = beta*dot*inv[s]*inv[d];
      atomicAdd(&cnt[d],1); }
    __syncthreads();
    if (t==0){ int o=0; for(int i=0;i<NQPG;i++){ off[i]=o; o+=cnt[i]; } }
    __syncthreads();
    if (t<NQPG){ woff[t]=off[t];
        if (cnt[t] > 0){
            float mm=-1e30f, dd=0.f;
            for (int j=0;j<EQPG;j++) if (dstl[j]==t) mm = fmaxf(mm, e[j]);
            for (int j=0;j<EQPG;j++) if (dstl[j]==t) dd += __expf(e[j]-mm);
            mx[t]=mm; den[t]=dd;
        } }
    __syncthreads();
    { int d = dstl[t];
      float dd = den[d];
      w[t] = dd > 0.f ? __expf(e[t]-mx[d]) / dd : 0.f;
      int pos = atomicAdd(&woff[d],1);
      csr[pos]=t; }
    __syncthreads();
    float aggr=0.f;
    { int d = t;
      for (int n=0;n<NQPG;n++){
          float acc=0.f;
          int o=off[n], c=cnt[n];
          for (int j=o;j<o+c;j++){ int ei=csr[j]; acc += w[ei]*h[srcl[ei]][d]; }
          h_q[(size_t)(g*NQPG+n)*128 + d] = f2bf(acc);
          aggr += acc;
      }
    }
    __syncthreads();
    part[t] = aggr*aggr;
    h[0][t] = aggr;          // stash hqa row for cvec (column t no longer read)
    __syncthreads();
    for (int s2=64; s2>0; s2>>=1){
        if (t<s2) part[t]+=part[t+s2];
        __syncthreads();
    }
    if (t==0) Qg[g]=part[0];
    float accc = 0.f;
    for (int k=0;k<128;k++) accc += h[0][k] * W1r_l[(128+k)*128 + t];
    cg2[g*128+t] = accc;
}

// ---- data-graph AGNN; precomputed CSR, 16-lane subwave edges/nodes (R6, 71us) ----
__global__ __launch_bounds__(1024) void k_gagnn(const unsigned short* __restrict__ h_g,
        const float* __restrict__ nrm2, const float* __restrict__ Qg,
        const unsigned short* __restrict__ srcl_g, const unsigned short* __restrict__ dstl_g,
        const unsigned short* __restrict__ csr_g, const int* __restrict__ off_g,
        const int* __restrict__ cnt_g, const float* __restrict__ beta_p,
        unsigned short* __restrict__ aout){
    int g = blockIdx.x, t = threadIdx.x;
    int wave = t>>6, lane = t&63, sub = lane>>4, sl = lane&15;
    __shared__ float e[EPG];
    __shared__ unsigned short srcl[EPG], dstl[EPG], csr[EPG];
    __shared__ float inv[NPG], mx[NPG], den[NPG];
    __shared__ int off[NPG];
    __shared__ unsigned short cnts[NPG];
    float beta = beta_p[0];
    float Q = Qg[g];
    int gbase = g*NPG;
    size_t ebase = (size_t)g*EPG;
    for (int i=t; i<EPG; i+=1024){
        srcl[i] = srcl_g[ebase+i];
        dstl[i] = dstl_g[ebase+i];
        csr[i]  = csr_g[ebase+i];
    }
    for (int n=t; n<NPG; n+=1024){
        inv[n] = rsqrtf(nrm2[gbase+n] + Q + 1e-24f);
        off[n] = off_g[g*NPG+n];
        cnts[n] = (unsigned short)cnt_g[g*NPG+n];
    }
    __syncthreads();
    for (int ei = wave*4 + sub; ei < EPG; ei += 64){
        int s = srcl[ei], d = dstl[ei];
        uint4 us = *(const uint4*)(h_g + (size_t)(gbase+s)*128 + sl*8);
        uint4 ud = *(const uint4*)(h_g + (size_t)(gbase+d)*128 + sl*8);
        float v = dot8(us, ud);
        v += __shfl_xor(v,1); v += __shfl_xor(v,2);
        v += __shfl_xor(v,4); v += __shfl_xor(v,8);
        if (sl==0) e[ei] = beta * (v + Q) * inv[s]*inv[d];
    }
    __syncthreads();
    for (int n=t; n<NPG; n+=1024){
        int c = cnts[n];
        if (c > 0){
            int o = off[n];
            float mm = -1e30f;
            for (int j=0;j<c;j++) mm = fmaxf(mm, e[csr[o+j]]);
            float dd = 0.f;
            for (int j=0;j<c;j++) dd += __expf(e[csr[o+j]]-mm);
            mx[n]=mm; den[n]=dd;
        }
    }
    __syncthreads();
    for (int i=t; i<EPG; i+=1024){
        int d = dstl[i];
        e[i] = __expf(e[i]-mx[d]) / den[d];
    }
    __syncthreads();
    for (int n = wave*4 + sub; n < NPG; n += 64){
        int c = cnts[n], o = off[n];
        float a0=0,a1=0,a2=0,a3=0,a4=0,a5=0,a6=0,a7=0;
        for (int j=0;j<c;j++){
            int ei = csr[o+j];
            float wg = e[ei];
            int s = srcl[ei];
            uint4 us = *(const uint4*)(h_g + (size_t)(gbase+s)*128 + sl*8);
            a0 = fmaf(wg, bf2f((unsigned short)(us.x&0xffff)), a0);
            a1 = fmaf(wg, bf2f((unsigned short)(us.x>>16)),   a1);
            a2 = fmaf(wg, bf2f((unsigned short)(us.y&0xffff)), a2);
            a3 = fmaf(wg, bf2f((unsigned short)(us.y>>16)),   a3);
            a4 = fmaf(wg, bf2f((unsigned short)(us.z&0xffff)), a4);
            a5 = fmaf(wg, bf2f((unsigned short)(us.z>>16)),   a5);
            a6 = fmaf(wg, bf2f((unsigned short)(us.w&0xffff)), a6);
            a7 = fmaf(wg, bf2f((unsigned short)(us.w>>16)),   a7);
        }
        uint4 ov;
        ov.x = (unsigned int)f2bf(a0) | ((unsigned int)f2bf(a1)<<16);
        ov.y = (unsigned int)f2bf(a2) | ((unsigned int)f2bf(a3)<<16);
        ov.z = (unsigned int)f2bf(a4) | ((unsigned int)f2bf(a5)<<16);
        ov.w = (unsigned int)f2bf(a6) | ((unsigned int)f2bf(a7)<<16);
        *(uint4*)(aout + (size_t)(gbase+n)*128 + sl*8) = ov;
    }
}

// ---- persistent fused MLP: one block per graph, weights staged in LDS ----
// LDS: W1s 128x136 + W2s 128x136 + h1 128x136 (bf16) = 102 KB -> 1 block/CU, 8 waves.
#define SMEM_MLP (3*128*136*2)
__global__ __launch_bounds__(512, 2) void k_mlp_p(const unsigned short* __restrict__ A,
        const unsigned short* __restrict__ W1t, const float* __restrict__ b1,
        const float* __restrict__ cg2, const float* __restrict__ degf,
        const unsigned short* __restrict__ W2t, const float* __restrict__ b2,
        unsigned short* __restrict__ out, float* __restrict__ nrm2){
    extern __shared__ __align__(16) char smem[];
    unsigned short* W1s = (unsigned short*)smem;       // 128 x 136
    unsigned short* W2s = W1s + 128*136;
    unsigned short* h1  = W2s + 128*136;
    int t = threadIdx.x;
    int g = blockIdx.x;
    // stage weights once (pitch 128 -> 136)
    #pragma unroll
    for (int p=0;p<4;p++){
        int flat = p*4096 + t*8;
        int n = flat>>7, k = flat&127;
        *(uint4*)(W1s + n*136 + k) = *(const uint4*)(W1t + n*128 + k);
        *(uint4*)(W2s + n*136 + k) = *(const uint4*)(W2t + n*128 + k);
    }
    __syncthreads();
    int wave = t>>6, lane = t&63, quad = lane>>4, l16 = lane&15;
    const float* cg = cg2 + (size_t)g*128;
    // prefetch A frags for tile 0
    short8 af[4];
    {
        int wrow = g*512 + wave*16;
        #pragma unroll
        for (int ks=0;ks<4;ks++)
            af[ks] = *(const short8*)(A + (size_t)(wrow+l16)*128 + ks*32 + quad*8);
    }
    for (int it=0; it<4; it++){
        int wrow = g*512 + it*128 + wave*16;
        // GEMM1
        floatx4 acc[8];
        #pragma unroll
        for (int t8=0;t8<8;t8++){
            #pragma unroll
            for (int r=0;r<4;r++) acc[t8][r]=0.f;
        }
        #pragma unroll
        for (int ks=0;ks<4;ks++){
            int koff = ks*32 + quad*8;
            #pragma unroll
            for (int t8=0;t8<8;t8++){
                short8 b = *(const short8*)(W1s + (t8*16+l16)*136 + koff);
                acc[t8] = __builtin_amdgcn_mfma_f32_16x16x32_bf16(af[ks], b, acc[t8], 0,0,0);
            }
        }
        float dg[4];
        #pragma unroll
        for (int r=0;r<4;r++) dg[r] = degf[wrow + quad*4 + r];
        #pragma unroll
        for (int t8=0;t8<8;t8++){
            int col = t8*16 + l16;
            float bv = b1[col];
            float cv = cg[col];
            #pragma unroll
            for (int r=0;r<4;r++){
                float v = acc[t8][r] + bv + dg[r]*cv;
                v = v > 0.f ? v : 0.f;
                h1[(wave*16 + quad*4 + r)*136 + col] = f2bf(v);
            }
        }
        __syncthreads();
        // prefetch next tile's A while GEMM2 runs from LDS
        short8 afn[4];
        if (it < 3){
            int wrow_n = g*512 + (it+1)*128 + wave*16;
            #pragma unroll
            for (int ks=0;ks<4;ks++)
                afn[ks] = *(const short8*)(A + (size_t)(wrow_n+l16)*128 + ks*32 + quad*8);
        }
        // GEMM2
        short8 hf[4];
        #pragma unroll
        for (int ks=0;ks<4;ks++) hf[ks] = *(const short8*)(h1 + (wave*16+l16)*136 + ks*32 + quad*8);
        floatx4 acc2[8];
        #pragma unroll
        for (int t8=0;t8<8;t8++){
            #pragma unroll
            for (int r=0;r<4;r++) acc2[t8][r]=0.f;
        }
        #pragma unroll
        for (int ks=0;ks<4;ks++){
            int koff = ks*32 + quad*8;
            #pragma unroll
            for (int t8=0;t8<8;t8++){
                short8 b = *(const short8*)(W2s + (t8*16+l16)*136 + koff);
                acc2[t8] = __builtin_amdgcn_mfma_f32_16x16x32_bf16(hf[ks], b, acc2[t8], 0,0,0);
            }
        }
        float ss[4] = {0.f,0.f,0.f,0.f};
        #pragma unroll
        for (int t8=0;t8<8;t8++){
            int col = t8*16 + l16;
            float bv = b2[col];
            #pragma unroll
            for (int r=0;r<4;r++){
                float v = acc2[t8][r] + bv;
                out[(size_t)(wrow + quad*4 + r)*128 + col] = f2bf(v);
                ss[r] += v*v;
            }
        }
        #pragma unroll
        for (int r=0;r<4;r++){
            #pragma unroll
            for (int o=1;o<16;o<<=1) ss[r] += __shfl_xor(ss[r], o);
        }
        if (l16==0){
            #pragma unroll
            for (int r=0;r<4;r++) nrm2[wrow + quad*4 + r] = ss[r];
        }
        __syncthreads();
        #pragma unroll
        for (int ks=0;ks<4;ks++) af[ks] = afn[ks];
    }
}

// ---- fused per-graph sum + predictor ----
__global__ __launch_bounds__(512) void k_hgpred(const unsigned short* __restrict__ h_g,
        const float* __restrict__ Wp1, const float* __restrict__ bp1,
        const float* __restrict__ Wp2, const float* __restrict__ bp2,
        float* __restrict__ y){
    __shared__ float red[32][128];
    __shared__ float hsum[128];
    __shared__ float red2[128];
    int g = blockIdx.x, t = threadIdx.x;
    int c = t & 15, r0 = t >> 4;
    float s[8];
    #pragma unroll
    for (int k=0;k<8;k++) s[k]=0.f;
    for (int i=0;i<16;i++){
        int row = r0 + i*32;
        uint4 u = *(const uint4*)(h_g + (size_t)(g*NPG + row)*128 + c*8);
        s[0] += bf2f((unsigned short)(u.x&0xffff)); s[1] += bf2f((unsigned short)(u.x>>16));
        s[2] += bf2f((unsigned short)(u.y&0xffff)); s[3] += bf2f((unsigned short)(u.y>>16));
        s[4] += bf2f((unsigned short)(u.z&0xffff)); s[5] += bf2f((unsigned short)(u.z>>16));
        s[6] += bf2f((unsigned short)(u.w&0xffff)); s[7] += bf2f((unsigned short)(u.w>>16));
    }
    #pragma unroll
    for (int k=0;k<8;k++) red[r0][c*8+k] = s[k];
    __syncthreads();
    if (t < 128){
        float a = 0.f;
        #pragma unroll
        for (int r=0;r<32;r++) a += red[r][t];
        hsum[t] = a;
    }
    __syncthreads();
    if (t < 128){
        float acc = bp1[t];
        for (int k=0;k<128;k++) acc += hsum[k]*Wp1[k*128+t];
        acc = fmaxf(acc, 0.f);
        red2[t] = acc * Wp2[t];
    }
    __syncthreads();
    for (int s2=64; s2>0; s2>>=1){
        if (t<s2) red2[t]+=red2[t+s2];
        __syncthreads();
    }
    if (t==0) y[g] = red2[0] + bp2[0];
}

extern "C" void kernel_launch(void* const* d_in, const int* in_sizes, int n_in,
                              void* d_out, int out_size, void* d_ws, size_t ws_size,
                              hipStream_t stream) {
    const float* X    = (const float*)d_in[0];
    const float* X_q  = (const float*)d_in[1];
    const int* g_src = (const int*)d_in[2];
    const int* g_dst = (const int*)d_in[3];
    const int* q_src = (const int*)d_in[5];
    const int* q_dst = (const int*)d_in[6];
    const float* Wg   = (const float*)d_in[8];
    const float* bg   = (const float*)d_in[9];
    const float* Wq   = (const float*)d_in[10];
    const float* bq   = (const float*)d_in[11];
    const float* betas_g = (const float*)d_in[12];
    const float* betas_q = (const float*)d_in[13];
    const float* W1r  = (const float*)d_in[14];
    const float* b1r  = (const float*)d_in[15];
    const float* W2r  = (const float*)d_in[16];
    const float* b2r  = (const float*)d_in[17];
    const float* Wp1  = (const float*)d_in[18];
    const float* bp1  = (const float*)d_in[19];
    const float* Wp2  = (const float*)d_in[20];
    const float* bp2  = (const float*)d_in[21];

    uint8_t* w = (uint8_t*)d_ws;
    unsigned short* h_g  = (unsigned short*)w;    w += (size_t)NG*128*2;
    unsigned short* h_q  = (unsigned short*)w;    w += (size_t)NQ*128*2;
    unsigned short* aout = (unsigned short*)w;    w += (size_t)NG*128*2;
    float* nrm2  = (float*)w;                     w += (size_t)NG*4;
    float* degf  = (float*)w;                     w += (size_t)NG*4;
    float* Qg    = (float*)w;                     w += (size_t)B_*4*4;
    float* cg2   = (float*)w;                     w += (size_t)B_*128*4;
    unsigned short* WgT   = (unsigned short*)w;   w += 8192*2;
    unsigned short* WqT   = (unsigned short*)w;   w += 8192*2;
    unsigned short* W1aT  = (unsigned short*)w;   w += 2*16384*2;
    unsigned short* W2rT  = (unsigned short*)w;   w += 2*16384*2;
    unsigned short* srcl_g = (unsigned short*)w;  w += (size_t)B_*EPG*2;
    unsigned short* dstl_g = (unsigned short*)w;  w += (size_t)B_*EPG*2;
    unsigned short* csr_g  = (unsigned short*)w;  w += (size_t)B_*EPG*2;
    int* off_g = (int*)w;                         w += (size_t)B_*NPG*4;
    int* cnt_g = (int*)w;                         w += (size_t)B_*NPG*4;

    static bool attr_done = false;
    if (!attr_done){
        hipFuncSetAttribute((const void*)k_mlp_p,
                            hipFuncAttributeMaxDynamicSharedMemorySize, SMEM_MLP);
        attr_done = true;
    }

    k_transpose<<<320,256,0,stream>>>(Wg,Wq,W1r,W2r,WgT,WqT,W1aT,W2rT);
    k_csr<<<B_,256,0,stream>>>(g_src,g_dst,srcl_g,dstl_g,csr_g,off_g,cnt_g,degf);
    k_proj<<<NG/64,256,0,stream>>>(X,   WgT, bg, h_g, nrm2);
    k_proj<<<NQ/64,256,0,stream>>>(X_q, WqT, bq, h_q, nullptr);
    for (int l=0;l<L_;l++){
        k_qagnn<<<B_,128,0,stream>>>(h_q, q_src, q_dst, betas_q + l, Qg,
                                     W1r + l*32768, cg2);
        k_gagnn<<<B_,1024,0,stream>>>(h_g, nrm2, Qg, srcl_g, dstl_g, csr_g, off_g,
                                      cnt_g, betas_g + l, aout);
        k_mlp_p<<<B_,512,SMEM_MLP,stream>>>(aout, W1aT + l*16384, b1r + l*128, cg2, degf,
                                            W2rT + l*16384, b2r + l*128, h_g, nrm2);
    }
    k_hgpred<<<B_,512,0,stream>>>(h_g, Wp1, bp1, Wp2, bp2, (float*)d_out);
}